// Round 6
// baseline (876.123 us; speedup 1.0000x reference)
//
#include <hip/hip_runtime.h>

// Event voxelization (QuantizationLayerBinary):
//   events [N,4] float32 rows (x, y, t, p) -> vox[2*C*H*W] set-to-1.0 scatter.
//   C=16, H=260, W=346. bin = ceil(t*C)-1, p in {-1,1} -> {0,1}.
//
// R1: float scatter into 11.5 MB out -> 548 MB HBM writes.
// R2: byte flags (2.88 MB) -> 788 MB writeback.
// R3: nt-load hint: -18% only (644 MB).
// R4: probe+atomicOr -> 3.4x slower; the DEPENDENT probe load blocked (~900cy
//     misses), but the atomics themselves ran in-cache (WRITE fell to 94 MB).
// R5: explicit buffer-load CPol SC1|NT = exact no-op vs R3. Conclusion: the
//     scattered stores MISS L2 and are not write-allocated — each miss is a
//     ~40 B fabric txn; L2 residency games can't fix the store path.
// R6: blind FIRE-AND-FORGET atomicOr into a 360 KiB u32 bitmask. No probe, no
//     return value -> issues like a store, executed at the coherent point
//     where the bitmask stays resident (R4 evidence). Expand decodes bits.

#define CBINS 16
#define HDIM  260
#define WDIM  346
#define NVOX  (2 * CBINS * HDIM * WDIM)   // 2,878,720
#define NWORDS (NVOX / 32)                // 89,960 u32 words (360 KiB)

typedef float fvec4 __attribute__((ext_vector_type(4)));

__global__ __launch_bounds__(256) void scatter_bits(const fvec4* __restrict__ ev,
                                                    unsigned int* __restrict__ bits,
                                                    int n) {
    int i = blockIdx.x * blockDim.x + threadIdx.x;
    if (i >= n) return;
    fvec4 e = __builtin_nontemporal_load(&ev[i]);   // x,y,t,p — streaming
    float t = e.z;
    if (t > 0.f && t <= 1.f) {
        int xi  = (int)e.x;
        int yi  = (int)e.y;
        int pi  = (e.w > 0.f) ? 1 : 0;     // (p_raw+1)*0.5 with p_raw in {-1,1}
        int bin = (int)ceilf(t * (float)CBINS) - 1;   // in [0,15] given valid t
        int idx = xi + WDIM * yi + WDIM * HDIM * (bin + CBINS * pi);
        // Blind fire-and-forget atomic: result unused -> global_atomic_or
        // without return; no dependent stall, RMW at the coherent point.
        atomicOr(&bits[(unsigned int)idx >> 5], 1u << (idx & 31));
    }
}

// Decode 4 bits -> one float4 nt store. Thread i covers voxels [4i, 4i+4).
__global__ __launch_bounds__(256) void expand_bits(const unsigned int* __restrict__ bits,
                                                   fvec4* __restrict__ out, int n4) {
    int i = blockIdx.x * blockDim.x + threadIdx.x;
    if (i >= n4) return;
    unsigned int word = bits[i >> 3];               // 8 threads share a word
    unsigned int nib  = (word >> ((i & 7) * 4)) & 0xFu;
    fvec4 v = { (nib & 1u) ? 1.f : 0.f, (nib & 2u) ? 1.f : 0.f,
                (nib & 4u) ? 1.f : 0.f, (nib & 8u) ? 1.f : 0.f };
    __builtin_nontemporal_store(v, &out[i]);        // streaming output
}

extern "C" void kernel_launch(void* const* d_in, const int* in_sizes, int n_in,
                              void* d_out, int out_size, void* d_ws, size_t ws_size,
                              hipStream_t stream) {
    const fvec4* ev = (const fvec4*)d_in[0];
    unsigned int* bits = (unsigned int*)d_ws;
    int n_events = in_sizes[0] / 4;        // 16,000,000
    int n4 = out_size / 4;                 // 719,680

    hipMemsetAsync(bits, 0, NWORDS * sizeof(unsigned int), stream);
    scatter_bits<<<(n_events + 255) / 256, 256, 0, stream>>>(ev, bits, n_events);
    expand_bits<<<(n4 + 255) / 256, 256, 0, stream>>>(bits, (fvec4*)d_out, n4);
}

// Round 7
// 390.886 us; speedup vs baseline: 2.2414x; 2.2414x over previous
//
#include <hip/hip_runtime.h>

// Event voxelization: events [N,4] f32 (x,y,t,p) -> vox[2*16*260*346] set-to-1.
//
// R1-R6 ledger: ANY random per-event access to the voxel region costs one
// ~32-40 B fabric transaction (stores don't write-allocate L2; cache hints
// no-op; atomics serialize at ~27 G/s). R3's 183 us IS that roofline.
// R7: eliminate random transactions: two-pass radix partition.
//   Pass 1: per-WG LDS counting sort by region (256 buckets of 11264 voxels),
//           coalesced chunk writes to idx_buf + bucket-major offset table.
//           Zero global atomics.
//   Pass 2: WG b gathers its runs (L3-resident), byte-flags in 11 KB LDS,
//           emits region as coalesced nt float4 (covers ALL of d_out).

#define CBINS 16
#define HDIM  260
#define WDIM  346
#define NVOX  (2 * CBINS * HDIM * WDIM)   // 2,878,720
#define NBUCK 256
#define RGN   11264                        // voxels/bucket; 256*11264 >= NVOX
#define CHUNK 7424                         // events per pass-1 WG (LDS <= 64 KB)
#define SENT  0xFFFFFFFFu

typedef float fvec4 __attribute__((ext_vector_type(4)));

__device__ __forceinline__ unsigned ev_to_idx(fvec4 e) {
    float t = e.z;
    if (!(t > 0.f && t <= 1.f)) return SENT;
    int xi  = (int)e.x;
    int yi  = (int)e.y;
    int pi  = (e.w > 0.f) ? 1 : 0;                 // p {-1,1} -> {0,1}
    int bin = (int)ceilf(t * (float)CBINS) - 1;    // [0,15]
    return (unsigned)(xi + WDIM * yi + WDIM * HDIM * (bin + CBINS * pi));
}

// ---------------- Pass 1: partition ----------------
__global__ __launch_bounds__(256) void partition_kernel(
        const fvec4* __restrict__ ev, int n,
        unsigned* __restrict__ idx_buf,      // [nchunk * CHUNK]
        unsigned* __restrict__ goff,         // [(NBUCK+1) * nchunk], bucket-major
        int nchunk) {
    __shared__ unsigned raw[CHUNK];          // 29,696 B
    __shared__ unsigned srt[CHUNK];          // 29,696 B
    __shared__ unsigned hist[NBUCK + 1];
    __shared__ unsigned scan[NBUCK];
    __shared__ unsigned cursor[NBUCK];

    const int w = blockIdx.x, tid = threadIdx.x;
    const int base = w * CHUNK;
    const int nev = min(CHUNK, n - base);

    for (int b = tid; b <= NBUCK; b += 256) hist[b] = 0;
    __syncthreads();

    // Phase A: load events (4x unrolled for MLP), idx -> LDS, histogram.
    int k = tid;
    for (; k + 768 < nev; k += 1024) {
        fvec4 e0 = __builtin_nontemporal_load(&ev[base + k]);
        fvec4 e1 = __builtin_nontemporal_load(&ev[base + k + 256]);
        fvec4 e2 = __builtin_nontemporal_load(&ev[base + k + 512]);
        fvec4 e3 = __builtin_nontemporal_load(&ev[base + k + 768]);
        unsigned i0 = ev_to_idx(e0), i1 = ev_to_idx(e1);
        unsigned i2 = ev_to_idx(e2), i3 = ev_to_idx(e3);
        raw[k]       = i0; raw[k + 256] = i1;
        raw[k + 512] = i2; raw[k + 768] = i3;
        atomicAdd(&hist[(i0 == SENT) ? NBUCK : i0 / (unsigned)RGN], 1u);
        atomicAdd(&hist[(i1 == SENT) ? NBUCK : i1 / (unsigned)RGN], 1u);
        atomicAdd(&hist[(i2 == SENT) ? NBUCK : i2 / (unsigned)RGN], 1u);
        atomicAdd(&hist[(i3 == SENT) ? NBUCK : i3 / (unsigned)RGN], 1u);
    }
    for (; k < nev; k += 256) {
        fvec4 e = __builtin_nontemporal_load(&ev[base + k]);
        unsigned i0 = ev_to_idx(e);
        raw[k] = i0;
        atomicAdd(&hist[(i0 == SENT) ? NBUCK : i0 / (unsigned)RGN], 1u);
    }
    __syncthreads();

    // Phase B: exclusive scan of hist[0..255] (Hillis-Steele, 256 threads).
    unsigned v = hist[tid];
    scan[tid] = v;
    __syncthreads();
    for (int s = 1; s < 256; s <<= 1) {
        unsigned add = (tid >= s) ? scan[tid - s] : 0u;
        __syncthreads();
        scan[tid] += add;
        __syncthreads();
    }
    unsigned excl = scan[tid] - v;
    cursor[tid] = excl;
    goff[tid * nchunk + w] = excl;                       // bucket-major table
    if (tid == 255) goff[NBUCK * nchunk + w] = scan[255]; // total valid
    __syncthreads();

    // Phase C: counting-sort into LDS (skip invalid).
    for (k = tid; k < nev; k += 256) {
        unsigned idx = raw[k];
        if (idx != SENT) {
            unsigned pos = atomicAdd(&cursor[idx / (unsigned)RGN], 1u);
            srt[pos] = idx;
        }
    }
    __syncthreads();

    // Phase D: coalesced contiguous chunk write.
    unsigned total = scan[255];
    unsigned cb = (unsigned)w * CHUNK;
    for (unsigned j = tid; j < total; j += 256) idx_buf[cb + j] = srt[j];
}

// ---------------- Pass 2: build output region ----------------
__global__ __launch_bounds__(1024) void build_kernel(
        const unsigned* __restrict__ idx_buf,
        const unsigned* __restrict__ goff,
        fvec4* __restrict__ out, int nchunk) {
    __shared__ unsigned char flag[RGN];      // 11,264 B
    const int b = blockIdx.x, tid = threadIdx.x;

    for (int i = tid; i < RGN / 4; i += 1024) ((unsigned*)flag)[i] = 0;
    __syncthreads();

    const unsigned rb = (unsigned)b * RGN;
    const unsigned* row0 = goff + (size_t)b * nchunk;
    const unsigned* row1 = row0 + nchunk;
    for (int w = tid; w < nchunk; w += 1024) {
        unsigned s = row0[w], e = row1[w];               // coalesced table reads
        const unsigned* p = idx_buf + (size_t)w * CHUNK;
        for (unsigned j = s; j < e; ++j)                  // ~29 seq reads: L1 hits
            flag[p[j] - rb] = 1;
    }
    __syncthreads();

    for (int i = tid; i < RGN / 4; i += 1024) {
        int g = b * (RGN / 4) + i;                        // float4 index
        if (g < NVOX / 4) {
            uchar4 f = ((const uchar4*)flag)[i];
            fvec4 vv = { f.x ? 1.f : 0.f, f.y ? 1.f : 0.f,
                         f.z ? 1.f : 0.f, f.w ? 1.f : 0.f };
            __builtin_nontemporal_store(vv, &out[g]);
        }
    }
}

// ---------------- Fallback (R3 path) if ws too small ----------------
__global__ __launch_bounds__(256) void scatter_flags(const fvec4* __restrict__ ev,
                                                     unsigned char* __restrict__ flags,
                                                     int n) {
    int i = blockIdx.x * blockDim.x + threadIdx.x;
    if (i >= n) return;
    unsigned idx = ev_to_idx(__builtin_nontemporal_load(&ev[i]));
    if (idx != SENT) flags[idx] = 1;
}
__global__ __launch_bounds__(256) void expand_flags(const uchar4* __restrict__ flags,
                                                    fvec4* __restrict__ out, int n4) {
    int i = blockIdx.x * blockDim.x + threadIdx.x;
    if (i >= n4) return;
    uchar4 f = flags[i];
    fvec4 v = { f.x ? 1.f : 0.f, f.y ? 1.f : 0.f, f.z ? 1.f : 0.f, f.w ? 1.f : 0.f };
    __builtin_nontemporal_store(v, &out[i]);
}

extern "C" void kernel_launch(void* const* d_in, const int* in_sizes, int n_in,
                              void* d_out, int out_size, void* d_ws, size_t ws_size,
                              hipStream_t stream) {
    const fvec4* ev = (const fvec4*)d_in[0];
    int n  = in_sizes[0] / 4;                // 16,000,000
    int n4 = out_size / 4;                   // 719,680
    int nchunk = (n + CHUNK - 1) / CHUNK;    // 2156

    size_t idx_bytes = (size_t)nchunk * CHUNK * sizeof(unsigned);
    size_t off_bytes = (size_t)(NBUCK + 1) * nchunk * sizeof(unsigned);

    if (ws_size >= idx_bytes + off_bytes) {
        unsigned* idx_buf = (unsigned*)d_ws;
        unsigned* goff    = (unsigned*)((char*)d_ws + idx_bytes);
        partition_kernel<<<nchunk, 256, 0, stream>>>(ev, n, idx_buf, goff, nchunk);
        build_kernel<<<NBUCK, 1024, 0, stream>>>(idx_buf, goff, (fvec4*)d_out, nchunk);
    } else {
        unsigned char* flags = (unsigned char*)d_ws;
        hipMemsetAsync(flags, 0, NVOX, stream);
        scatter_flags<<<(n + 255) / 256, 256, 0, stream>>>(ev, flags, n);
        expand_flags<<<(n4 + 255) / 256, 256, 0, stream>>>((const uchar4*)flags,
                                                           (fvec4*)d_out, n4);
    }
}